// Round 3
// baseline (1207.214 us; speedup 1.0000x reference)
//
#include <hip/hip_runtime.h>
#include <hip/hip_fp16.h>

// Sinkhorn OT: n=m=4096, d=32, reg=0.1, 100 iterations, uniform marginals.
// R8 = R7 with the fence compile fix (__hip_atomic_fence is not exposed by
// this ROCm; use __builtin_amdgcn_fence(order, "agent") instead).
// Structure: ONE persistent cooperative kernel for all 100 iterations:
//   - eliminates ~200 graph dispatch boundaries (~0.8-1 us each)
//   - hand-rolled 2-level grid barrier (8 spread counter lines, agent-scope
//     fences for cross-XCD visibility per Guideline 16)
//   - K-row prefetch issued BEFORE the barrier (K immutable -> stale-safe),
//     hiding matrix-load latency under barrier arrival/spin
//   - freeze (v16 bitwise 2-periodicity) becomes a uniform `break`: frozen
//     iterations cost zero instead of a dead dispatch each
// Fallback: if hipLaunchCooperativeKernel fails under capture, replay the R6
// per-iteration dispatch loop (identical math).

#define NN 4096
#define MM 4096
#define DD 32
#define N_ITERS 100

static constexpr float INV_REG = 10.0f;
static constexpr float A_MARG  = 1.0f / 4096.0f;
static constexpr float B_MARG  = 1.0f / 4096.0f;

typedef _Float16 h2_t __attribute__((ext_vector_type(2)));

static __device__ __forceinline__ float dot2(unsigned a, unsigned b, float acc) {
#if __has_builtin(__builtin_amdgcn_fdot2)
    return __builtin_amdgcn_fdot2(__builtin_bit_cast(h2_t, a),
                                  __builtin_bit_cast(h2_t, b), acc, false);
#else
    float2 fa = __half22float2(*(const __half2*)&a);
    float2 fb = __half22float2(*(const __half2*)&b);
    acc = fmaf(fa.x, fb.x, acc);
    return fmaf(fa.y, fb.y, acc);
#endif
}

static __device__ __forceinline__ void fence_release_agent() {
#if __has_builtin(__builtin_amdgcn_fence)
    __builtin_amdgcn_fence(__ATOMIC_RELEASE, "agent");
#else
    __threadfence();
#endif
}
static __device__ __forceinline__ void fence_acquire_agent() {
#if __has_builtin(__builtin_amdgcn_fence)
    __builtin_amdgcn_fence(__ATOMIC_ACQUIRE, "agent");
#else
    __threadfence();
#endif
}

static __device__ __forceinline__ unsigned ld_dev_u32(const unsigned* p) {
    return __hip_atomic_load(p, __ATOMIC_RELAXED, __HIP_MEMORY_SCOPE_AGENT);
}
static __device__ __forceinline__ void st_dev_u32(unsigned* p, unsigned v) {
    __hip_atomic_store(p, v, __ATOMIC_RELAXED, __HIP_MEMORY_SCOPE_AGENT);
}
static __device__ __forceinline__ unsigned short ld_dev_u16(const unsigned short* p) {
    return __hip_atomic_load(p, __ATOMIC_RELAXED, __HIP_MEMORY_SCOPE_AGENT);
}
static __device__ __forceinline__ void st_dev_u16(unsigned short* p, unsigned short v) {
    __hip_atomic_store(p, v, __ATOMIC_RELAXED, __HIP_MEMORY_SCOPE_AGENT);
}

// ---------------------------------------------------------------------------
// 2-level grid barrier for 512 co-resident blocks. Arrival: one relaxed
// atomicAdd per block into counter line (bid & 7) (8 lines x 128 B apart ->
// parallel TCC channels, 64 adds/line). Wait: first wave's lanes 0..7 each
// poll one line until all reach 64*p. Release fence before arrival flushes
// this XCD's dirty u/v lines; acquire fence after spin invalidates stale
// cached copies (same cache behavior as a dispatch boundary today).
// ---------------------------------------------------------------------------
static __device__ __forceinline__ void gbar(unsigned* cnt8, unsigned p) {
    __syncthreads();
    if (threadIdx.x < 64) {
        const int l = threadIdx.x;
        if (l == 0) {
            fence_release_agent();
            __hip_atomic_fetch_add(cnt8 + (blockIdx.x & 7) * 32, 1u,
                                   __ATOMIC_RELAXED, __HIP_MEMORY_SCOPE_AGENT);
        }
        const unsigned tgt = p * 64u;
        for (;;) {
            bool ok = true;
            if (l < 8)
                ok = (__hip_atomic_load(cnt8 + l * 32, __ATOMIC_RELAXED,
                                        __HIP_MEMORY_SCOPE_AGENT) >= tgt);
            if (__all(ok)) break;
            __builtin_amdgcn_s_sleep(1);
        }
        if (l == 0) fence_acquire_agent();
    }
    __syncthreads();
}

// ---------------------------------------------------------------------------
// Kh[i][j] = (half)exp(-||p_i - q_j||^2 / reg). prime!=0: v16=1/4096,
// conv=0, slot=1, barrier counters zeroed.
// grid: (4096/256, 4096/16), block 256
// ---------------------------------------------------------------------------
__global__ void compute_K_half(const float* __restrict__ p, const float* __restrict__ q,
                               __half* __restrict__ Kh, __half* __restrict__ v16,
                               unsigned* __restrict__ conv, unsigned* __restrict__ slot,
                               unsigned* __restrict__ cnt8, int prime) {
    const int tid = threadIdx.x;
    const int j   = blockIdx.x * 256 + tid;
    const int r0  = blockIdx.y * 16;

    if (prime && blockIdx.y == 0) {
        v16[j] = __float2half(B_MARG);
        if (blockIdx.x == 0) {
            if (tid == 0) { *conv = 0u; *slot = 1u; }
            if (tid < 256) cnt8[tid] = 0u;
        }
    }

    float qv[DD];
    const float4* q4 = (const float4*)(q + (size_t)j * DD);
#pragma unroll
    for (int k = 0; k < DD / 4; ++k) {
        float4 t = q4[k];
        qv[4 * k + 0] = t.x; qv[4 * k + 1] = t.y;
        qv[4 * k + 2] = t.z; qv[4 * k + 3] = t.w;
    }

    __shared__ float ps[16 * DD];
    ps[tid]       = p[(size_t)r0 * DD + tid];
    ps[tid + 256] = p[(size_t)r0 * DD + tid + 256];
    __syncthreads();

#pragma unroll 4
    for (int ii = 0; ii < 16; ++ii) {
        float acc = 0.0f;
#pragma unroll
        for (int k = 0; k < DD; ++k) {
            float d = ps[ii * DD + k] - qv[k];
            acc = fmaf(d, d, acc);
        }
        Kh[(size_t)(r0 + ii) * MM + j] = __float2half(__expf(-acc * INV_REG));
    }
}

// ---------------------------------------------------------------------------
// Persistent kernel: all 100 iterations. 512 blocks x 1024 thr (16 waves),
// 2 waves per row, 4 independent fdot2 chains, LDS partial combine.
// Bit-identical accumulation order to the R6 rowpass pair.
// ---------------------------------------------------------------------------
__global__ void __launch_bounds__(1024, 8)
sinkhorn_persist(const __half* __restrict__ Kh, const __half* __restrict__ KTh,
                 float* __restrict__ u32, __half* __restrict__ u16,
                 float* __restrict__ v32, __half* __restrict__ v16,
                 unsigned short* __restrict__ hist,
                 unsigned* __restrict__ slot, unsigned* __restrict__ cnt8) {
    __shared__ __align__(16) __half vlds[MM];
    __shared__ float part[16];
    const int tid  = threadIdx.x;
    const int lane = tid & 63;
    const int w    = tid >> 6;          // wave 0..15
    const int rib  = w >> 1;            // row-in-block 0..7
    const int hlf  = w & 1;             // which half-row
    const int i    = blockIdx.x * 8 + rib;
    const int g0   = hlf * 256 + lane;  // uint4 index into 512-uint4 row
    const uint4* __restrict__ MU = (const uint4*)(Kh  + (size_t)i * MM);
    const uint4* __restrict__ MV = (const uint4*)(KTh + (size_t)i * MM);

    unsigned p = 0;

    // prefetch u-half matrix rows for t=0
    uint4 k0 = MU[g0], k1 = MU[g0 + 64], k2 = MU[g0 + 128], k3 = MU[g0 + 192];

    for (int t = 0; t < N_ITERS; ++t) {
        if ((t & 1) == 0) {
            if (t != 0 && ld_dev_u32(slot) == 0u) break;   // frozen: exact
        } else {
            if (blockIdx.x == 0 && tid == 0) st_dev_u32(slot, 0u);
        }

        // ---------------- u-half: u = a / (Kh . v16) ----------------
        if (tid < 512) { uint4 s = ((const uint4*)v16)[tid]; ((uint4*)vlds)[tid] = s; }
        __syncthreads();
        {
            const uint4* V = (const uint4*)vlds;
            const uint4 a = V[g0], b = V[g0 + 64], c = V[g0 + 128], d = V[g0 + 192];
            float x0 = 0.f, x1 = 0.f, x2 = 0.f, x3 = 0.f;
            x0 = dot2(k0.x, a.x, x0); x0 = dot2(k0.y, a.y, x0);
            x0 = dot2(k0.z, a.z, x0); x0 = dot2(k0.w, a.w, x0);
            x1 = dot2(k1.x, b.x, x1); x1 = dot2(k1.y, b.y, x1);
            x1 = dot2(k1.z, b.z, x1); x1 = dot2(k1.w, b.w, x1);
            x2 = dot2(k2.x, c.x, x2); x2 = dot2(k2.y, c.y, x2);
            x2 = dot2(k2.z, c.z, x2); x2 = dot2(k2.w, c.w, x2);
            x3 = dot2(k3.x, d.x, x3); x3 = dot2(k3.y, d.y, x3);
            x3 = dot2(k3.z, d.z, x3); x3 = dot2(k3.w, d.w, x3);
            float acc = (x0 + x1) + (x2 + x3);
#pragma unroll
            for (int off = 32; off > 0; off >>= 1) acc += __shfl_down(acc, off, 64);
            if (lane == 0) part[w] = acc;
        }
        // prefetch v-half rows (K immutable -> safe across barrier)
        k0 = MV[g0]; k1 = MV[g0 + 64]; k2 = MV[g0 + 128]; k3 = MV[g0 + 192];
        __syncthreads();
        if (tid < 8) {
            const int row = blockIdx.x * 8 + tid;
            float r = A_MARG / (part[2 * tid] + part[2 * tid + 1]);
            u32[row] = r;
            u16[row] = __float2half(r);
        }
        gbar(cnt8, ++p);

        // ---------------- v-half: v = b / (KTh . u16) ----------------
        if (tid < 512) { uint4 s = ((const uint4*)u16)[tid]; ((uint4*)vlds)[tid] = s; }
        __syncthreads();
        {
            const uint4* V = (const uint4*)vlds;
            const uint4 a = V[g0], b = V[g0 + 64], c = V[g0 + 128], d = V[g0 + 192];
            float x0 = 0.f, x1 = 0.f, x2 = 0.f, x3 = 0.f;
            x0 = dot2(k0.x, a.x, x0); x0 = dot2(k0.y, a.y, x0);
            x0 = dot2(k0.z, a.z, x0); x0 = dot2(k0.w, a.w, x0);
            x1 = dot2(k1.x, b.x, x1); x1 = dot2(k1.y, b.y, x1);
            x1 = dot2(k1.z, b.z, x1); x1 = dot2(k1.w, b.w, x1);
            x2 = dot2(k2.x, c.x, x2); x2 = dot2(k2.y, c.y, x2);
            x2 = dot2(k2.z, c.z, x2); x2 = dot2(k2.w, c.w, x2);
            x3 = dot2(k3.x, d.x, x3); x3 = dot2(k3.y, d.y, x3);
            x3 = dot2(k3.z, d.z, x3); x3 = dot2(k3.w, d.w, x3);
            float acc = (x0 + x1) + (x2 + x3);
#pragma unroll
            for (int off = 32; off > 0; off >>= 1) acc += __shfl_down(acc, off, 64);
            if (lane == 0) part[w] = acc;
        }
        // prefetch next u-half rows
        k0 = MU[g0]; k1 = MU[g0 + 64]; k2 = MU[g0 + 128]; k3 = MU[g0 + 192];
        __syncthreads();
        if (tid < 8) {
            const int row = blockIdx.x * 8 + tid;
            float r = B_MARG / (part[2 * tid] + part[2 * tid + 1]);
            v32[row] = r;
            const __half h = __float2half(r);
            if (t & 1) {
                const unsigned short bits = __half_as_ushort(h);
                const unsigned short old2 = ld_dev_u16(hist + row);
                if (old2 != bits) st_dev_u32(slot, 1u);
                st_dev_u16(hist + row, bits);
            }
            v16[row] = h;
        }
        gbar(cnt8, ++p);
    }
}

// ---------------------------------------------------------------------------
// Fallback per-iteration rowpasses (identical to R6; used only if the
// cooperative launch is rejected under graph capture).
// ---------------------------------------------------------------------------
__global__ void __launch_bounds__(1024, 8)
rowpass_u(const __half* __restrict__ Mat, const __half* __restrict__ w16_in,
          float* __restrict__ w32_out, __half* __restrict__ w16_out,
          unsigned* __restrict__ conv, unsigned* __restrict__ slot, int t) {
    if (ld_dev_u32(conv)) return;
    if ((t & 1) == 0) {
        if (ld_dev_u32(slot) == 0u) {
            if (threadIdx.x == 0) st_dev_u32(conv, 1u);
            return;
        }
    } else {
        if (blockIdx.x == 0 && threadIdx.x == 0) st_dev_u32(slot, 0u);
    }

    __shared__ __align__(16) __half vlds[MM];
    __shared__ float part[16];
    const int tid  = threadIdx.x;
    const int lane = tid & 63;
    const int w    = tid >> 6;
    const int rib  = w >> 1;
    const int hlf  = w & 1;
    const int i    = blockIdx.x * 8 + rib;
    const uint4* __restrict__ Mrow = (const uint4*)(Mat + (size_t)i * MM);
    const int g0 = hlf * 256 + lane;

    uint4 stg;
    if (tid < 512) stg = ((const uint4*)w16_in)[tid];
    const uint4 k0 = Mrow[g0];
    const uint4 k1 = Mrow[g0 + 64];
    const uint4 k2 = Mrow[g0 + 128];
    const uint4 k3 = Mrow[g0 + 192];
    if (tid < 512) ((uint4*)vlds)[tid] = stg;
    __syncthreads();

    const uint4* V = (const uint4*)vlds;
    const uint4 v0 = V[g0];
    const uint4 v1 = V[g0 + 64];
    const uint4 v2 = V[g0 + 128];
    const uint4 v3 = V[g0 + 192];

    float a0 = 0.f, a1 = 0.f, a2 = 0.f, a3 = 0.f;
    a0 = dot2(k0.x, v0.x, a0); a0 = dot2(k0.y, v0.y, a0);
    a0 = dot2(k0.z, v0.z, a0); a0 = dot2(k0.w, v0.w, a0);
    a1 = dot2(k1.x, v1.x, a1); a1 = dot2(k1.y, v1.y, a1);
    a1 = dot2(k1.z, v1.z, a1); a1 = dot2(k1.w, v1.w, a1);
    a2 = dot2(k2.x, v2.x, a2); a2 = dot2(k2.y, v2.y, a2);
    a2 = dot2(k2.z, v2.z, a2); a2 = dot2(k2.w, v2.w, a2);
    a3 = dot2(k3.x, v3.x, a3); a3 = dot2(k3.y, v3.y, a3);
    a3 = dot2(k3.z, v3.z, a3); a3 = dot2(k3.w, v3.w, a3);
    float acc = (a0 + a1) + (a2 + a3);

#pragma unroll
    for (int off = 32; off > 0; off >>= 1) acc += __shfl_down(acc, off, 64);
    if (lane == 0) part[w] = acc;
    __syncthreads();

    if (tid < 8) {
        const int row = blockIdx.x * 8 + tid;
        float r = A_MARG / (part[2 * tid] + part[2 * tid + 1]);
        w32_out[row] = r;
        w16_out[row] = __float2half(r);
    }
}

__global__ void __launch_bounds__(1024, 8)
rowpass_v(const __half* __restrict__ Mat, const __half* __restrict__ w16_in,
          float* __restrict__ w32_out, __half* __restrict__ w16_out,
          unsigned short* __restrict__ hist,
          unsigned* __restrict__ conv, unsigned* __restrict__ slot, int t) {
    if (ld_dev_u32(conv)) return;

    __shared__ __align__(16) __half vlds[MM];
    __shared__ float part[16];
    const int tid  = threadIdx.x;
    const int lane = tid & 63;
    const int w    = tid >> 6;
    const int rib  = w >> 1;
    const int hlf  = w & 1;
    const int i    = blockIdx.x * 8 + rib;
    const uint4* __restrict__ Mrow = (const uint4*)(Mat + (size_t)i * MM);
    const int g0 = hlf * 256 + lane;

    uint4 stg;
    if (tid < 512) stg = ((const uint4*)w16_in)[tid];
    const uint4 k0 = Mrow[g0];
    const uint4 k1 = Mrow[g0 + 64];
    const uint4 k2 = Mrow[g0 + 128];
    const uint4 k3 = Mrow[g0 + 192];
    if (tid < 512) ((uint4*)vlds)[tid] = stg;
    __syncthreads();

    const uint4* V = (const uint4*)vlds;
    const uint4 v0 = V[g0];
    const uint4 v1 = V[g0 + 64];
    const uint4 v2 = V[g0 + 128];
    const uint4 v3 = V[g0 + 192];

    float a0 = 0.f, a1 = 0.f, a2 = 0.f, a3 = 0.f;
    a0 = dot2(k0.x, v0.x, a0); a0 = dot2(k0.y, v0.y, a0);
    a0 = dot2(k0.z, v0.z, a0); a0 = dot2(k0.w, v0.w, a0);
    a1 = dot2(k1.x, v1.x, a1); a1 = dot2(k1.y, v1.y, a1);
    a1 = dot2(k1.z, v1.z, a1); a1 = dot2(k1.w, v1.w, a1);
    a2 = dot2(k2.x, v2.x, a2); a2 = dot2(k2.y, v2.y, a2);
    a2 = dot2(k2.z, v2.z, a2); a2 = dot2(k2.w, v2.w, a2);
    a3 = dot2(k3.x, v3.x, a3); a3 = dot2(k3.y, v3.y, a3);
    a3 = dot2(k3.z, v3.z, a3); a3 = dot2(k3.w, v3.w, a3);
    float acc = (a0 + a1) + (a2 + a3);

#pragma unroll
    for (int off = 32; off > 0; off >>= 1) acc += __shfl_down(acc, off, 64);
    if (lane == 0) part[w] = acc;
    __syncthreads();

    if (tid < 8) {
        const int row = blockIdx.x * 8 + tid;
        float r = B_MARG / (part[2 * tid] + part[2 * tid + 1]);
        w32_out[row] = r;
        const __half h = __float2half(r);
        if (t & 1) {
            const unsigned short bits = __half_as_ushort(h);
            const unsigned short old2 = ld_dev_u16(hist + row);
            if (old2 != bits) st_dev_u32(slot, 1u);
            st_dev_u16(hist + row, bits);
        }
        w16_out[row] = h;
    }
}

// ---------------------------------------------------------------------------
// gamma[i][j] = u[i] * exp(-||x_i-y_j||^2/reg) * v[j]   (exact fp32 K)
// grid: (16, 256), block 256
// ---------------------------------------------------------------------------
__global__ void epilogue(const float* __restrict__ x, const float* __restrict__ y,
                         const float* __restrict__ u, const float* __restrict__ v,
                         float* __restrict__ out) {
    const int tid = threadIdx.x;
    const int j   = blockIdx.x * 256 + tid;
    const int r0  = blockIdx.y * 16;

    float yv[DD];
    const float4* y4 = (const float4*)(y + (size_t)j * DD);
#pragma unroll
    for (int k = 0; k < DD / 4; ++k) {
        float4 t = y4[k];
        yv[4 * k + 0] = t.x; yv[4 * k + 1] = t.y;
        yv[4 * k + 2] = t.z; yv[4 * k + 3] = t.w;
    }

    __shared__ float xs[16 * DD];
    __shared__ float u_lds[16];
    xs[tid]       = x[(size_t)r0 * DD + tid];
    xs[tid + 256] = x[(size_t)r0 * DD + tid + 256];
    if (tid < 16) u_lds[tid] = u[r0 + tid];
    __syncthreads();

    const float vj = v[j];
#pragma unroll 4
    for (int ii = 0; ii < 16; ++ii) {
        float acc = 0.0f;
#pragma unroll
        for (int k = 0; k < DD; ++k) {
            float d = xs[ii * DD + k] - yv[k];
            acc = fmaf(d, d, acc);
        }
        out[(size_t)(r0 + ii) * MM + j] = u_lds[ii] * __expf(-acc * INV_REG) * vj;
    }
}

extern "C" void kernel_launch(void* const* d_in, const int* in_sizes, int n_in,
                              void* d_out, int out_size, void* d_ws, size_t ws_size,
                              hipStream_t stream) {
    const float* x = (const float*)d_in[0];
    const float* y = (const float*)d_in[1];
    __half*   Kh   = (__half*)d_ws;                    // 32 MB
    __half*   KTh  = Kh + (size_t)NN * MM;             // 32 MB
    float*    u32  = (float*)(KTh + (size_t)NN * MM);  // 16 KB
    float*    v32  = u32 + NN;                         // 16 KB
    __half*   u16  = (__half*)(v32 + MM);              // 8 KB
    __half*   v16  = u16 + NN;                         // 8 KB
    unsigned short* hist = (unsigned short*)(v16 + MM);// 8 KB (0xAA-poison safe)
    unsigned* slot = (unsigned*)(hist + MM);           // 4 B
    unsigned* conv = slot + 1;                         // 4 B (fallback path)
    unsigned* cnt8 = slot + 32;                        // 1 KB barrier counters
    float*    out  = (float*)d_out;

    compute_K_half<<<dim3(MM / 256, NN / 16), 256, 0, stream>>>(x, y, Kh, v16, conv, slot, cnt8, 1);
    compute_K_half<<<dim3(NN / 256, MM / 16), 256, 0, stream>>>(y, x, KTh, v16, conv, slot, cnt8, 0);

    {
        void* args[] = { &Kh, &KTh, &u32, &u16, &v32, &v16, &hist, &slot, &cnt8 };
        hipError_t e = hipLaunchCooperativeKernel((const void*)sinkhorn_persist,
                                                  dim3(512), dim3(1024), args, 0, stream);
        if (e != hipSuccess) {
            (void)hipGetLastError();   // clear; fall back to per-iteration dispatches
            for (int t = 0; t < N_ITERS; ++t) {
                rowpass_u<<<NN / 8, 1024, 0, stream>>>(Kh,  v16, u32, u16, conv, slot, t);
                rowpass_v<<<MM / 8, 1024, 0, stream>>>(KTh, u16, v32, v16, hist, conv, slot, t);
            }
        }
    }

    epilogue<<<dim3(MM / 256, NN / 16), 256, 0, stream>>>(x, y, u32, v32, out);
}

// Round 4
// 653.201 us; speedup vs baseline: 1.8482x; 1.8482x over previous
//
#include <hip/hip_runtime.h>
#include <hip/hip_fp16.h>

// Sinkhorn OT: n=m=4096, d=32, reg=0.1, 100 iterations, uniform marginals.
// R9 = R8 persistent cooperative kernel, with the agent-scope FENCES REMOVED
// from the grid barrier. R8 post-mortem: the acquire/release agent fences
// invalidated/writeback'd the per-XCD L2 (+L1) 200 times, evicting the
// read-only 64 MB K/K^T working set every pass (5.15 us/pass, VALUBusy 2%).
// Coherence is instead carried by the DATA accesses:
//   - u16/v16/slot writes: agent-scope relaxed atomic stores (write-through
//     past the non-coherent L2 to the coherence point)
//   - u16/v16 staging reads: agent-scope relaxed atomic loads (bypass L1/L2)
//   - ordering: explicit s_waitcnt vmcnt(0) before the barrier-arrival add
//     (all cross-block-visible stores are issued by wave 0, same wave as the
//     arrival), plus __syncthreads' documented vmcnt drain
// K/K^T remain plain cached loads and now stay L1/L2-resident across ALL
// iterations (impossible with per-iteration dispatches, which invalidate L1).
// Freeze (v16 bitwise 2-periodicity) stays a uniform `break`.
// Fallback: R6 per-iteration dispatch loop if cooperative launch fails.

#define NN 4096
#define MM 4096
#define DD 32
#define N_ITERS 100

static constexpr float INV_REG = 10.0f;
static constexpr float A_MARG  = 1.0f / 4096.0f;
static constexpr float B_MARG  = 1.0f / 4096.0f;

typedef _Float16 h2_t __attribute__((ext_vector_type(2)));

static __device__ __forceinline__ float dot2(unsigned a, unsigned b, float acc) {
#if __has_builtin(__builtin_amdgcn_fdot2)
    return __builtin_amdgcn_fdot2(__builtin_bit_cast(h2_t, a),
                                  __builtin_bit_cast(h2_t, b), acc, false);
#else
    float2 fa = __half22float2(*(const __half2*)&a);
    float2 fb = __half22float2(*(const __half2*)&b);
    acc = fmaf(fa.x, fb.x, acc);
    return fmaf(fa.y, fb.y, acc);
#endif
}

static __device__ __forceinline__ unsigned ld_dev_u32(const unsigned* p) {
    return __hip_atomic_load(p, __ATOMIC_RELAXED, __HIP_MEMORY_SCOPE_AGENT);
}
static __device__ __forceinline__ void st_dev_u32(unsigned* p, unsigned v) {
    __hip_atomic_store(p, v, __ATOMIC_RELAXED, __HIP_MEMORY_SCOPE_AGENT);
}
static __device__ __forceinline__ unsigned short ld_dev_u16(const unsigned short* p) {
    return __hip_atomic_load(p, __ATOMIC_RELAXED, __HIP_MEMORY_SCOPE_AGENT);
}
static __device__ __forceinline__ void st_dev_u16(unsigned short* p, unsigned short v) {
    __hip_atomic_store(p, v, __ATOMIC_RELAXED, __HIP_MEMORY_SCOPE_AGENT);
}
static __device__ __forceinline__ unsigned long long ld_dev_u64(const unsigned long long* p) {
    return __hip_atomic_load(p, __ATOMIC_RELAXED, __HIP_MEMORY_SCOPE_AGENT);
}

// ---------------------------------------------------------------------------
// Fence-free 2-level grid barrier for 512 co-resident blocks.
// Arrival: one relaxed atomicAdd per block into counter line (bid & 7)
// (8 lines x 128 B apart, 64 adds/line). The arriving lane first drains
// vmcnt(0): every cross-block-visible store (u16/v16/slot atomics) was
// issued by THIS wave (wave 0), so the drain puts them at the coherence
// point before the counter increments. Wait: wave 0 lanes 0..7 poll the 8
// lines (agent-scope loads bypass stale caches). No cache-flush fences:
// K/K^T stay resident in L1/L2 across the whole run.
// ---------------------------------------------------------------------------
static __device__ __forceinline__ void gbar(unsigned* cnt8, unsigned p) {
    __syncthreads();
    if (threadIdx.x < 64) {
        const int l = threadIdx.x;
        if (l == 0) {
            asm volatile("s_waitcnt vmcnt(0)" ::: "memory");
            __hip_atomic_fetch_add(cnt8 + (blockIdx.x & 7) * 32, 1u,
                                   __ATOMIC_RELAXED, __HIP_MEMORY_SCOPE_AGENT);
        }
        const unsigned tgt = p * 64u;
        for (;;) {
            bool ok = true;
            if (l < 8)
                ok = (__hip_atomic_load(cnt8 + l * 32, __ATOMIC_RELAXED,
                                        __HIP_MEMORY_SCOPE_AGENT) >= tgt);
            if (__all(ok)) break;
            __builtin_amdgcn_s_sleep(1);
        }
    }
    __syncthreads();
}

// ---------------------------------------------------------------------------
// Kh[i][j] = (half)exp(-||p_i - q_j||^2 / reg). prime!=0: v16=1/4096,
// conv=0, slot=1, barrier counters zeroed.
// grid: (4096/256, 4096/16), block 256
// ---------------------------------------------------------------------------
__global__ void compute_K_half(const float* __restrict__ p, const float* __restrict__ q,
                               __half* __restrict__ Kh, __half* __restrict__ v16,
                               unsigned* __restrict__ conv, unsigned* __restrict__ slot,
                               unsigned* __restrict__ cnt8, int prime) {
    const int tid = threadIdx.x;
    const int j   = blockIdx.x * 256 + tid;
    const int r0  = blockIdx.y * 16;

    if (prime && blockIdx.y == 0) {
        v16[j] = __float2half(B_MARG);
        if (blockIdx.x == 0) {
            if (tid == 0) { *conv = 0u; *slot = 1u; }
            if (tid < 256) cnt8[tid] = 0u;
        }
    }

    float qv[DD];
    const float4* q4 = (const float4*)(q + (size_t)j * DD);
#pragma unroll
    for (int k = 0; k < DD / 4; ++k) {
        float4 t = q4[k];
        qv[4 * k + 0] = t.x; qv[4 * k + 1] = t.y;
        qv[4 * k + 2] = t.z; qv[4 * k + 3] = t.w;
    }

    __shared__ float ps[16 * DD];
    ps[tid]       = p[(size_t)r0 * DD + tid];
    ps[tid + 256] = p[(size_t)r0 * DD + tid + 256];
    __syncthreads();

#pragma unroll 4
    for (int ii = 0; ii < 16; ++ii) {
        float acc = 0.0f;
#pragma unroll
        for (int k = 0; k < DD; ++k) {
            float d = ps[ii * DD + k] - qv[k];
            acc = fmaf(d, d, acc);
        }
        Kh[(size_t)(r0 + ii) * MM + j] = __float2half(__expf(-acc * INV_REG));
    }
}

// ---------------------------------------------------------------------------
// Persistent kernel: all 100 iterations. 512 blocks x 1024 thr (16 waves),
// 2 waves per row, 4 independent fdot2 chains, LDS partial combine.
// Bit-identical accumulation order to the R6 rowpass pair.
// ---------------------------------------------------------------------------
__global__ void __launch_bounds__(1024, 8)
sinkhorn_persist(const __half* __restrict__ Kh, const __half* __restrict__ KTh,
                 float* __restrict__ u32, __half* __restrict__ u16,
                 float* __restrict__ v32, __half* __restrict__ v16,
                 unsigned short* __restrict__ hist,
                 unsigned* __restrict__ slot, unsigned* __restrict__ cnt8) {
    __shared__ __align__(16) __half vlds[MM];
    __shared__ float part[16];
    const int tid  = threadIdx.x;
    const int lane = tid & 63;
    const int w    = tid >> 6;          // wave 0..15
    const int rib  = w >> 1;            // row-in-block 0..7
    const int hlf  = w & 1;             // which half-row
    const int i    = blockIdx.x * 8 + rib;
    const int g0   = hlf * 256 + lane;  // uint4 index into 512-uint4 row
    const uint4* __restrict__ MU = (const uint4*)(Kh  + (size_t)i * MM);
    const uint4* __restrict__ MV = (const uint4*)(KTh + (size_t)i * MM);

    unsigned p = 0;

    // prefetch u-half matrix rows for t=0
    uint4 k0 = MU[g0], k1 = MU[g0 + 64], k2 = MU[g0 + 128], k3 = MU[g0 + 192];

    for (int t = 0; t < N_ITERS; ++t) {
        if ((t & 1) == 0) {
            if (t != 0 && ld_dev_u32(slot) == 0u) break;   // frozen: exact
        } else {
            if (blockIdx.x == 0 && tid == 0) st_dev_u32(slot, 0u);
        }

        // ---------------- u-half: u = a / (Kh . v16) ----------------
        if (tid < 512) {   // coherent (cache-bypass) read of freshly-written v16
            const unsigned long long* s64 = (const unsigned long long*)v16;
            unsigned long long lo = ld_dev_u64(s64 + 2 * tid);
            unsigned long long hi = ld_dev_u64(s64 + 2 * tid + 1);
            ((unsigned long long*)vlds)[2 * tid]     = lo;
            ((unsigned long long*)vlds)[2 * tid + 1] = hi;
        }
        __syncthreads();
        {
            const uint4* V = (const uint4*)vlds;
            const uint4 a = V[g0], b = V[g0 + 64], c = V[g0 + 128], d = V[g0 + 192];
            float x0 = 0.f, x1 = 0.f, x2 = 0.f, x3 = 0.f;
            x0 = dot2(k0.x, a.x, x0); x0 = dot2(k0.y, a.y, x0);
            x0 = dot2(k0.z, a.z, x0); x0 = dot2(k0.w, a.w, x0);
            x1 = dot2(k1.x, b.x, x1); x1 = dot2(k1.y, b.y, x1);
            x1 = dot2(k1.z, b.z, x1); x1 = dot2(k1.w, b.w, x1);
            x2 = dot2(k2.x, c.x, x2); x2 = dot2(k2.y, c.y, x2);
            x2 = dot2(k2.z, c.z, x2); x2 = dot2(k2.w, c.w, x2);
            x3 = dot2(k3.x, d.x, x3); x3 = dot2(k3.y, d.y, x3);
            x3 = dot2(k3.z, d.z, x3); x3 = dot2(k3.w, d.w, x3);
            float acc = (x0 + x1) + (x2 + x3);
#pragma unroll
            for (int off = 32; off > 0; off >>= 1) acc += __shfl_down(acc, off, 64);
            if (lane == 0) part[w] = acc;
        }
        // prefetch v-half rows (K immutable -> safe across barrier)
        k0 = MV[g0]; k1 = MV[g0 + 64]; k2 = MV[g0 + 128]; k3 = MV[g0 + 192];
        __syncthreads();
        if (tid < 8) {
            const int row = blockIdx.x * 8 + tid;
            float r = A_MARG / (part[2 * tid] + part[2 * tid + 1]);
            u32[row] = r;
            st_dev_u16((unsigned short*)u16 + row, __half_as_ushort(__float2half(r)));
        }
        gbar(cnt8, ++p);

        // ---------------- v-half: v = b / (KTh . u16) ----------------
        if (tid < 512) {
            const unsigned long long* s64 = (const unsigned long long*)u16;
            unsigned long long lo = ld_dev_u64(s64 + 2 * tid);
            unsigned long long hi = ld_dev_u64(s64 + 2 * tid + 1);
            ((unsigned long long*)vlds)[2 * tid]     = lo;
            ((unsigned long long*)vlds)[2 * tid + 1] = hi;
        }
        __syncthreads();
        {
            const uint4* V = (const uint4*)vlds;
            const uint4 a = V[g0], b = V[g0 + 64], c = V[g0 + 128], d = V[g0 + 192];
            float x0 = 0.f, x1 = 0.f, x2 = 0.f, x3 = 0.f;
            x0 = dot2(k0.x, a.x, x0); x0 = dot2(k0.y, a.y, x0);
            x0 = dot2(k0.z, a.z, x0); x0 = dot2(k0.w, a.w, x0);
            x1 = dot2(k1.x, b.x, x1); x1 = dot2(k1.y, b.y, x1);
            x1 = dot2(k1.z, b.z, x1); x1 = dot2(k1.w, b.w, x1);
            x2 = dot2(k2.x, c.x, x2); x2 = dot2(k2.y, c.y, x2);
            x2 = dot2(k2.z, c.z, x2); x2 = dot2(k2.w, c.w, x2);
            x3 = dot2(k3.x, d.x, x3); x3 = dot2(k3.y, d.y, x3);
            x3 = dot2(k3.z, d.z, x3); x3 = dot2(k3.w, d.w, x3);
            float acc = (x0 + x1) + (x2 + x3);
#pragma unroll
            for (int off = 32; off > 0; off >>= 1) acc += __shfl_down(acc, off, 64);
            if (lane == 0) part[w] = acc;
        }
        // prefetch next u-half rows
        k0 = MU[g0]; k1 = MU[g0 + 64]; k2 = MU[g0 + 128]; k3 = MU[g0 + 192];
        __syncthreads();
        if (tid < 8) {
            const int row = blockIdx.x * 8 + tid;
            float r = B_MARG / (part[2 * tid] + part[2 * tid + 1]);
            v32[row] = r;
            const __half h = __float2half(r);
            const unsigned short bits = __half_as_ushort(h);
            if (t & 1) {
                const unsigned short old2 = ld_dev_u16(hist + row);
                if (old2 != bits) st_dev_u32(slot, 1u);
                st_dev_u16(hist + row, bits);
            }
            st_dev_u16((unsigned short*)v16 + row, bits);
        }
        gbar(cnt8, ++p);
    }
}

// ---------------------------------------------------------------------------
// Fallback per-iteration rowpasses (identical to R6; used only if the
// cooperative launch is rejected under graph capture).
// ---------------------------------------------------------------------------
__global__ void __launch_bounds__(1024, 8)
rowpass_u(const __half* __restrict__ Mat, const __half* __restrict__ w16_in,
          float* __restrict__ w32_out, __half* __restrict__ w16_out,
          unsigned* __restrict__ conv, unsigned* __restrict__ slot, int t) {
    if (ld_dev_u32(conv)) return;
    if ((t & 1) == 0) {
        if (ld_dev_u32(slot) == 0u) {
            if (threadIdx.x == 0) st_dev_u32(conv, 1u);
            return;
        }
    } else {
        if (blockIdx.x == 0 && threadIdx.x == 0) st_dev_u32(slot, 0u);
    }

    __shared__ __align__(16) __half vlds[MM];
    __shared__ float part[16];
    const int tid  = threadIdx.x;
    const int lane = tid & 63;
    const int w    = tid >> 6;
    const int rib  = w >> 1;
    const int hlf  = w & 1;
    const int i    = blockIdx.x * 8 + rib;
    const uint4* __restrict__ Mrow = (const uint4*)(Mat + (size_t)i * MM);
    const int g0 = hlf * 256 + lane;

    uint4 stg;
    if (tid < 512) stg = ((const uint4*)w16_in)[tid];
    const uint4 k0 = Mrow[g0];
    const uint4 k1 = Mrow[g0 + 64];
    const uint4 k2 = Mrow[g0 + 128];
    const uint4 k3 = Mrow[g0 + 192];
    if (tid < 512) ((uint4*)vlds)[tid] = stg;
    __syncthreads();

    const uint4* V = (const uint4*)vlds;
    const uint4 v0 = V[g0];
    const uint4 v1 = V[g0 + 64];
    const uint4 v2 = V[g0 + 128];
    const uint4 v3 = V[g0 + 192];

    float a0 = 0.f, a1 = 0.f, a2 = 0.f, a3 = 0.f;
    a0 = dot2(k0.x, v0.x, a0); a0 = dot2(k0.y, v0.y, a0);
    a0 = dot2(k0.z, v0.z, a0); a0 = dot2(k0.w, v0.w, a0);
    a1 = dot2(k1.x, v1.x, a1); a1 = dot2(k1.y, v1.y, a1);
    a1 = dot2(k1.z, v1.z, a1); a1 = dot2(k1.w, v1.w, a1);
    a2 = dot2(k2.x, v2.x, a2); a2 = dot2(k2.y, v2.y, a2);
    a2 = dot2(k2.z, v2.z, a2); a2 = dot2(k2.w, v2.w, a2);
    a3 = dot2(k3.x, v3.x, a3); a3 = dot2(k3.y, v3.y, a3);
    a3 = dot2(k3.z, v3.z, a3); a3 = dot2(k3.w, v3.w, a3);
    float acc = (a0 + a1) + (a2 + a3);

#pragma unroll
    for (int off = 32; off > 0; off >>= 1) acc += __shfl_down(acc, off, 64);
    if (lane == 0) part[w] = acc;
    __syncthreads();

    if (tid < 8) {
        const int row = blockIdx.x * 8 + tid;
        float r = A_MARG / (part[2 * tid] + part[2 * tid + 1]);
        w32_out[row] = r;
        w16_out[row] = __float2half(r);
    }
}

__global__ void __launch_bounds__(1024, 8)
rowpass_v(const __half* __restrict__ Mat, const __half* __restrict__ w16_in,
          float* __restrict__ w32_out, __half* __restrict__ w16_out,
          unsigned short* __restrict__ hist,
          unsigned* __restrict__ conv, unsigned* __restrict__ slot, int t) {
    if (ld_dev_u32(conv)) return;

    __shared__ __align__(16) __half vlds[MM];
    __shared__ float part[16];
    const int tid  = threadIdx.x;
    const int lane = tid & 63;
    const int w    = tid >> 6;
    const int rib  = w >> 1;
    const int hlf  = w & 1;
    const int i    = blockIdx.x * 8 + rib;
    const uint4* __restrict__ Mrow = (const uint4*)(Mat + (size_t)i * MM);
    const int g0 = hlf * 256 + lane;

    uint4 stg;
    if (tid < 512) stg = ((const uint4*)w16_in)[tid];
    const uint4 k0 = Mrow[g0];
    const uint4 k1 = Mrow[g0 + 64];
    const uint4 k2 = Mrow[g0 + 128];
    const uint4 k3 = Mrow[g0 + 192];
    if (tid < 512) ((uint4*)vlds)[tid] = stg;
    __syncthreads();

    const uint4* V = (const uint4*)vlds;
    const uint4 v0 = V[g0];
    const uint4 v1 = V[g0 + 64];
    const uint4 v2 = V[g0 + 128];
    const uint4 v3 = V[g0 + 192];

    float a0 = 0.f, a1 = 0.f, a2 = 0.f, a3 = 0.f;
    a0 = dot2(k0.x, v0.x, a0); a0 = dot2(k0.y, v0.y, a0);
    a0 = dot2(k0.z, v0.z, a0); a0 = dot2(k0.w, v0.w, a0);
    a1 = dot2(k1.x, v1.x, a1); a1 = dot2(k1.y, v1.y, a1);
    a1 = dot2(k1.z, v1.z, a1); a1 = dot2(k1.w, v1.w, a1);
    a2 = dot2(k2.x, v2.x, a2); a2 = dot2(k2.y, v2.y, a2);
    a2 = dot2(k2.z, v2.z, a2); a2 = dot2(k2.w, v2.w, a2);
    a3 = dot2(k3.x, v3.x, a3); a3 = dot2(k3.y, v3.y, a3);
    a3 = dot2(k3.z, v3.z, a3); a3 = dot2(k3.w, v3.w, a3);
    float acc = (a0 + a1) + (a2 + a3);

#pragma unroll
    for (int off = 32; off > 0; off >>= 1) acc += __shfl_down(acc, off, 64);
    if (lane == 0) part[w] = acc;
    __syncthreads();

    if (tid < 8) {
        const int row = blockIdx.x * 8 + tid;
        float r = B_MARG / (part[2 * tid] + part[2 * tid + 1]);
        w32_out[row] = r;
        const __half h = __float2half(r);
        if (t & 1) {
            const unsigned short bits = __half_as_ushort(h);
            const unsigned short old2 = ld_dev_u16(hist + row);
            if (old2 != bits) st_dev_u32(slot, 1u);
            st_dev_u16(hist + row, bits);
        }
        w16_out[row] = h;
    }
}

// ---------------------------------------------------------------------------
// gamma[i][j] = u[i] * exp(-||x_i-y_j||^2/reg) * v[j]   (exact fp32 K)
// grid: (16, 256), block 256
// ---------------------------------------------------------------------------
__global__ void epilogue(const float* __restrict__ x, const float* __restrict__ y,
                         const float* __restrict__ u, const float* __restrict__ v,
                         float* __restrict__ out) {
    const int tid = threadIdx.x;
    const int j   = blockIdx.x * 256 + tid;
    const int r0  = blockIdx.y * 16;

    float yv[DD];
    const float4* y4 = (const float4*)(y + (size_t)j * DD);
#pragma unroll
    for (int k = 0; k < DD / 4; ++k) {
        float4 t = y4[k];
        yv[4 * k + 0] = t.x; yv[4 * k + 1] = t.y;
        yv[4 * k + 2] = t.z; yv[4 * k + 3] = t.w;
    }

    __shared__ float xs[16 * DD];
    __shared__ float u_lds[16];
    xs[tid]       = x[(size_t)r0 * DD + tid];
    xs[tid + 256] = x[(size_t)r0 * DD + tid + 256];
    if (tid < 16) u_lds[tid] = u[r0 + tid];
    __syncthreads();

    const float vj = v[j];
#pragma unroll 4
    for (int ii = 0; ii < 16; ++ii) {
        float acc = 0.0f;
#pragma unroll
        for (int k = 0; k < DD; ++k) {
            float d = xs[ii * DD + k] - yv[k];
            acc = fmaf(d, d, acc);
        }
        out[(size_t)(r0 + ii) * MM + j] = u_lds[ii] * __expf(-acc * INV_REG) * vj;
    }
}

extern "C" void kernel_launch(void* const* d_in, const int* in_sizes, int n_in,
                              void* d_out, int out_size, void* d_ws, size_t ws_size,
                              hipStream_t stream) {
    const float* x = (const float*)d_in[0];
    const float* y = (const float*)d_in[1];
    __half*   Kh   = (__half*)d_ws;                    // 32 MB
    __half*   KTh  = Kh + (size_t)NN * MM;             // 32 MB
    float*    u32  = (float*)(KTh + (size_t)NN * MM);  // 16 KB
    float*    v32  = u32 + NN;                         // 16 KB
    __half*   u16  = (__half*)(v32 + MM);              // 8 KB
    __half*   v16  = u16 + NN;                         // 8 KB
    unsigned short* hist = (unsigned short*)(v16 + MM);// 8 KB (0xAA-poison safe)
    unsigned* slot = (unsigned*)(hist + MM);           // 4 B
    unsigned* conv = slot + 1;                         // 4 B (fallback path)
    unsigned* cnt8 = slot + 32;                        // 1 KB barrier counters
    float*    out  = (float*)d_out;

    compute_K_half<<<dim3(MM / 256, NN / 16), 256, 0, stream>>>(x, y, Kh, v16, conv, slot, cnt8, 1);
    compute_K_half<<<dim3(NN / 256, MM / 16), 256, 0, stream>>>(y, x, KTh, v16, conv, slot, cnt8, 0);

    {
        void* args[] = { &Kh, &KTh, &u32, &u16, &v32, &v16, &hist, &slot, &cnt8 };
        hipError_t e = hipLaunchCooperativeKernel((const void*)sinkhorn_persist,
                                                  dim3(512), dim3(1024), args, 0, stream);
        if (e != hipSuccess) {
            (void)hipGetLastError();   // clear; fall back to per-iteration dispatches
            for (int t = 0; t < N_ITERS; ++t) {
                rowpass_u<<<NN / 8, 1024, 0, stream>>>(Kh,  v16, u32, u16, conv, slot, t);
                rowpass_v<<<MM / 8, 1024, 0, stream>>>(KTh, u16, v32, v16, hist, conv, slot, t);
            }
        }
    }

    epilogue<<<dim3(MM / 256, NN / 16), 256, 0, stream>>>(x, y, u32, v32, out);
}

// Round 5
// 637.539 us; speedup vs baseline: 1.8936x; 1.0246x over previous
//
#include <hip/hip_runtime.h>
#include <hip/hip_fp16.h>

// Sinkhorn OT: n=m=4096, d=32, reg=0.1, 100 iterations, uniform marginals.
// R10 = R9 (fence-free persistent cooperative kernel) + L2 CACHE PARTITIONING:
// R9 post-mortem: per-XCD working set (K+K^T rows) is 8 MB cycling over a
// 4 MB L2 -> LRU worst case, ~0% L2 hits; everything streams from L3 at
// ~13 TB/s in BOTH the dispatch-loop and persistent designs. Fix: mark the
// v-half (K^T) matrix loads NON-TEMPORAL (no L2 allocation). The u-half (K)
// rows are exactly 4 MB/XCD = L2 capacity and can now stay L2-resident for
// all 100 iterations (only possible in-persistent-kernel: dispatch
// boundaries writeback-invalidate L2).
// Coherence for u/v/slot is carried by agent-scope atomic loads/stores +
// s_waitcnt vmcnt(0) before barrier arrival (same wave issues both).
// Freeze (v16 bitwise 2-periodicity) stays a uniform `break`.
// Fallback: R6 per-iteration dispatch loop if cooperative launch fails.

#define NN 4096
#define MM 4096
#define DD 32
#define N_ITERS 100

static constexpr float INV_REG = 10.0f;
static constexpr float A_MARG  = 1.0f / 4096.0f;
static constexpr float B_MARG  = 1.0f / 4096.0f;

typedef _Float16 h2_t __attribute__((ext_vector_type(2)));
typedef unsigned u32v4 __attribute__((ext_vector_type(4)));

static __device__ __forceinline__ float dot2(unsigned a, unsigned b, float acc) {
#if __has_builtin(__builtin_amdgcn_fdot2)
    return __builtin_amdgcn_fdot2(__builtin_bit_cast(h2_t, a),
                                  __builtin_bit_cast(h2_t, b), acc, false);
#else
    float2 fa = __half22float2(*(const __half2*)&a);
    float2 fb = __half22float2(*(const __half2*)&b);
    acc = fmaf(fa.x, fb.x, acc);
    return fmaf(fa.y, fb.y, acc);
#endif
}

// Non-temporal 16B load: nt flag -> no L2 allocation, K^T streaming cannot
// evict the L2-resident K half. Data-identical to a plain load.
static __device__ __forceinline__ uint4 ld_nt_u4(const uint4* p) {
#if __has_builtin(__builtin_nontemporal_load)
    u32v4 r = __builtin_nontemporal_load((const u32v4*)p);
    uint4 o; o.x = r[0]; o.y = r[1]; o.z = r[2]; o.w = r[3];
    return o;
#else
    return *p;
#endif
}

static __device__ __forceinline__ unsigned ld_dev_u32(const unsigned* p) {
    return __hip_atomic_load(p, __ATOMIC_RELAXED, __HIP_MEMORY_SCOPE_AGENT);
}
static __device__ __forceinline__ void st_dev_u32(unsigned* p, unsigned v) {
    __hip_atomic_store(p, v, __ATOMIC_RELAXED, __HIP_MEMORY_SCOPE_AGENT);
}
static __device__ __forceinline__ unsigned short ld_dev_u16(const unsigned short* p) {
    return __hip_atomic_load(p, __ATOMIC_RELAXED, __HIP_MEMORY_SCOPE_AGENT);
}
static __device__ __forceinline__ void st_dev_u16(unsigned short* p, unsigned short v) {
    __hip_atomic_store(p, v, __ATOMIC_RELAXED, __HIP_MEMORY_SCOPE_AGENT);
}
static __device__ __forceinline__ unsigned long long ld_dev_u64(const unsigned long long* p) {
    return __hip_atomic_load(p, __ATOMIC_RELAXED, __HIP_MEMORY_SCOPE_AGENT);
}

// ---------------------------------------------------------------------------
// Fence-free 2-level grid barrier for 512 co-resident blocks (see R9 notes).
// ---------------------------------------------------------------------------
static __device__ __forceinline__ void gbar(unsigned* cnt8, unsigned p) {
    __syncthreads();
    if (threadIdx.x < 64) {
        const int l = threadIdx.x;
        if (l == 0) {
            asm volatile("s_waitcnt vmcnt(0)" ::: "memory");
            __hip_atomic_fetch_add(cnt8 + (blockIdx.x & 7) * 32, 1u,
                                   __ATOMIC_RELAXED, __HIP_MEMORY_SCOPE_AGENT);
        }
        const unsigned tgt = p * 64u;
        for (;;) {
            bool ok = true;
            if (l < 8)
                ok = (__hip_atomic_load(cnt8 + l * 32, __ATOMIC_RELAXED,
                                        __HIP_MEMORY_SCOPE_AGENT) >= tgt);
            if (__all(ok)) break;
            __builtin_amdgcn_s_sleep(1);
        }
    }
    __syncthreads();
}

// ---------------------------------------------------------------------------
// Kh[i][j] = (half)exp(-||p_i - q_j||^2 / reg). prime!=0: v16=1/4096,
// conv=0, slot=1, barrier counters zeroed.
// grid: (4096/256, 4096/16), block 256
// ---------------------------------------------------------------------------
__global__ void compute_K_half(const float* __restrict__ p, const float* __restrict__ q,
                               __half* __restrict__ Kh, __half* __restrict__ v16,
                               unsigned* __restrict__ conv, unsigned* __restrict__ slot,
                               unsigned* __restrict__ cnt8, int prime) {
    const int tid = threadIdx.x;
    const int j   = blockIdx.x * 256 + tid;
    const int r0  = blockIdx.y * 16;

    if (prime && blockIdx.y == 0) {
        v16[j] = __float2half(B_MARG);
        if (blockIdx.x == 0) {
            if (tid == 0) { *conv = 0u; *slot = 1u; }
            if (tid < 256) cnt8[tid] = 0u;
        }
    }

    float qv[DD];
    const float4* q4 = (const float4*)(q + (size_t)j * DD);
#pragma unroll
    for (int k = 0; k < DD / 4; ++k) {
        float4 t = q4[k];
        qv[4 * k + 0] = t.x; qv[4 * k + 1] = t.y;
        qv[4 * k + 2] = t.z; qv[4 * k + 3] = t.w;
    }

    __shared__ float ps[16 * DD];
    ps[tid]       = p[(size_t)r0 * DD + tid];
    ps[tid + 256] = p[(size_t)r0 * DD + tid + 256];
    __syncthreads();

#pragma unroll 4
    for (int ii = 0; ii < 16; ++ii) {
        float acc = 0.0f;
#pragma unroll
        for (int k = 0; k < DD; ++k) {
            float d = ps[ii * DD + k] - qv[k];
            acc = fmaf(d, d, acc);
        }
        Kh[(size_t)(r0 + ii) * MM + j] = __float2half(__expf(-acc * INV_REG));
    }
}

// ---------------------------------------------------------------------------
// Persistent kernel: all 100 iterations. 512 blocks x 1024 thr (16 waves),
// 2 waves per row, 4 independent fdot2 chains, LDS partial combine.
// u-half K loads: plain cached (L2-resident, 4 MB/XCD).
// v-half K^T loads: non-temporal (stream from L3, no L2 pollution).
// Bit-identical accumulation order to the R6 rowpass pair.
// ---------------------------------------------------------------------------
__global__ void __launch_bounds__(1024, 8)
sinkhorn_persist(const __half* __restrict__ Kh, const __half* __restrict__ KTh,
                 float* __restrict__ u32, __half* __restrict__ u16,
                 float* __restrict__ v32, __half* __restrict__ v16,
                 unsigned short* __restrict__ hist,
                 unsigned* __restrict__ slot, unsigned* __restrict__ cnt8) {
    __shared__ __align__(16) __half vlds[MM];
    __shared__ float part[16];
    const int tid  = threadIdx.x;
    const int lane = tid & 63;
    const int w    = tid >> 6;          // wave 0..15
    const int rib  = w >> 1;            // row-in-block 0..7
    const int hlf  = w & 1;             // which half-row
    const int i    = blockIdx.x * 8 + rib;
    const int g0   = hlf * 256 + lane;  // uint4 index into 512-uint4 row
    const uint4* __restrict__ MU = (const uint4*)(Kh  + (size_t)i * MM);
    const uint4* __restrict__ MV = (const uint4*)(KTh + (size_t)i * MM);

    unsigned p = 0;

    // prefetch u-half matrix rows for t=0
    uint4 k0 = MU[g0], k1 = MU[g0 + 64], k2 = MU[g0 + 128], k3 = MU[g0 + 192];

    for (int t = 0; t < N_ITERS; ++t) {
        if ((t & 1) == 0) {
            if (t != 0 && ld_dev_u32(slot) == 0u) break;   // frozen: exact
        } else {
            if (blockIdx.x == 0 && tid == 0) st_dev_u32(slot, 0u);
        }

        // ---------------- u-half: u = a / (Kh . v16) ----------------
        if (tid < 512) {   // coherent (cache-bypass) read of freshly-written v16
            const unsigned long long* s64 = (const unsigned long long*)v16;
            unsigned long long lo = ld_dev_u64(s64 + 2 * tid);
            unsigned long long hi = ld_dev_u64(s64 + 2 * tid + 1);
            ((unsigned long long*)vlds)[2 * tid]     = lo;
            ((unsigned long long*)vlds)[2 * tid + 1] = hi;
        }
        __syncthreads();
        {
            const uint4* V = (const uint4*)vlds;
            const uint4 a = V[g0], b = V[g0 + 64], c = V[g0 + 128], d = V[g0 + 192];
            float x0 = 0.f, x1 = 0.f, x2 = 0.f, x3 = 0.f;
            x0 = dot2(k0.x, a.x, x0); x0 = dot2(k0.y, a.y, x0);
            x0 = dot2(k0.z, a.z, x0); x0 = dot2(k0.w, a.w, x0);
            x1 = dot2(k1.x, b.x, x1); x1 = dot2(k1.y, b.y, x1);
            x1 = dot2(k1.z, b.z, x1); x1 = dot2(k1.w, b.w, x1);
            x2 = dot2(k2.x, c.x, x2); x2 = dot2(k2.y, c.y, x2);
            x2 = dot2(k2.z, c.z, x2); x2 = dot2(k2.w, c.w, x2);
            x3 = dot2(k3.x, d.x, x3); x3 = dot2(k3.y, d.y, x3);
            x3 = dot2(k3.z, d.z, x3); x3 = dot2(k3.w, d.w, x3);
            float acc = (x0 + x1) + (x2 + x3);
#pragma unroll
            for (int off = 32; off > 0; off >>= 1) acc += __shfl_down(acc, off, 64);
            if (lane == 0) part[w] = acc;
        }
        // prefetch v-half rows: NON-TEMPORAL (no L2 allocation -> K stays hot)
        k0 = ld_nt_u4(MV + g0);
        k1 = ld_nt_u4(MV + g0 + 64);
        k2 = ld_nt_u4(MV + g0 + 128);
        k3 = ld_nt_u4(MV + g0 + 192);
        __syncthreads();
        if (tid < 8) {
            const int row = blockIdx.x * 8 + tid;
            float r = A_MARG / (part[2 * tid] + part[2 * tid + 1]);
            u32[row] = r;
            st_dev_u16((unsigned short*)u16 + row, __half_as_ushort(__float2half(r)));
        }
        gbar(cnt8, ++p);

        // ---------------- v-half: v = b / (KTh . u16) ----------------
        if (tid < 512) {
            const unsigned long long* s64 = (const unsigned long long*)u16;
            unsigned long long lo = ld_dev_u64(s64 + 2 * tid);
            unsigned long long hi = ld_dev_u64(s64 + 2 * tid + 1);
            ((unsigned long long*)vlds)[2 * tid]     = lo;
            ((unsigned long long*)vlds)[2 * tid + 1] = hi;
        }
        __syncthreads();
        {
            const uint4* V = (const uint4*)vlds;
            const uint4 a = V[g0], b = V[g0 + 64], c = V[g0 + 128], d = V[g0 + 192];
            float x0 = 0.f, x1 = 0.f, x2 = 0.f, x3 = 0.f;
            x0 = dot2(k0.x, a.x, x0); x0 = dot2(k0.y, a.y, x0);
            x0 = dot2(k0.z, a.z, x0); x0 = dot2(k0.w, a.w, x0);
            x1 = dot2(k1.x, b.x, x1); x1 = dot2(k1.y, b.y, x1);
            x1 = dot2(k1.z, b.z, x1); x1 = dot2(k1.w, b.w, x1);
            x2 = dot2(k2.x, c.x, x2); x2 = dot2(k2.y, c.y, x2);
            x2 = dot2(k2.z, c.z, x2); x2 = dot2(k2.w, c.w, x2);
            x3 = dot2(k3.x, d.x, x3); x3 = dot2(k3.y, d.y, x3);
            x3 = dot2(k3.z, d.z, x3); x3 = dot2(k3.w, d.w, x3);
            float acc = (x0 + x1) + (x2 + x3);
#pragma unroll
            for (int off = 32; off > 0; off >>= 1) acc += __shfl_down(acc, off, 64);
            if (lane == 0) part[w] = acc;
        }
        // prefetch next u-half rows: plain cached (L2-resident half)
        k0 = MU[g0]; k1 = MU[g0 + 64]; k2 = MU[g0 + 128]; k3 = MU[g0 + 192];
        __syncthreads();
        if (tid < 8) {
            const int row = blockIdx.x * 8 + tid;
            float r = B_MARG / (part[2 * tid] + part[2 * tid + 1]);
            v32[row] = r;
            const __half h = __float2half(r);
            const unsigned short bits = __half_as_ushort(h);
            if (t & 1) {
                const unsigned short old2 = ld_dev_u16(hist + row);
                if (old2 != bits) st_dev_u32(slot, 1u);
                st_dev_u16(hist + row, bits);
            }
            st_dev_u16((unsigned short*)v16 + row, bits);
        }
        gbar(cnt8, ++p);
    }
}

// ---------------------------------------------------------------------------
// Fallback per-iteration rowpasses (identical to R6; used only if the
// cooperative launch is rejected under graph capture).
// ---------------------------------------------------------------------------
__global__ void __launch_bounds__(1024, 8)
rowpass_u(const __half* __restrict__ Mat, const __half* __restrict__ w16_in,
          float* __restrict__ w32_out, __half* __restrict__ w16_out,
          unsigned* __restrict__ conv, unsigned* __restrict__ slot, int t) {
    if (ld_dev_u32(conv)) return;
    if ((t & 1) == 0) {
        if (ld_dev_u32(slot) == 0u) {
            if (threadIdx.x == 0) st_dev_u32(conv, 1u);
            return;
        }
    } else {
        if (blockIdx.x == 0 && threadIdx.x == 0) st_dev_u32(slot, 0u);
    }

    __shared__ __align__(16) __half vlds[MM];
    __shared__ float part[16];
    const int tid  = threadIdx.x;
    const int lane = tid & 63;
    const int w    = tid >> 6;
    const int rib  = w >> 1;
    const int hlf  = w & 1;
    const int i    = blockIdx.x * 8 + rib;
    const uint4* __restrict__ Mrow = (const uint4*)(Mat + (size_t)i * MM);
    const int g0 = hlf * 256 + lane;

    uint4 stg;
    if (tid < 512) stg = ((const uint4*)w16_in)[tid];
    const uint4 k0 = Mrow[g0];
    const uint4 k1 = Mrow[g0 + 64];
    const uint4 k2 = Mrow[g0 + 128];
    const uint4 k3 = Mrow[g0 + 192];
    if (tid < 512) ((uint4*)vlds)[tid] = stg;
    __syncthreads();

    const uint4* V = (const uint4*)vlds;
    const uint4 v0 = V[g0];
    const uint4 v1 = V[g0 + 64];
    const uint4 v2 = V[g0 + 128];
    const uint4 v3 = V[g0 + 192];

    float a0 = 0.f, a1 = 0.f, a2 = 0.f, a3 = 0.f;
    a0 = dot2(k0.x, v0.x, a0); a0 = dot2(k0.y, v0.y, a0);
    a0 = dot2(k0.z, v0.z, a0); a0 = dot2(k0.w, v0.w, a0);
    a1 = dot2(k1.x, v1.x, a1); a1 = dot2(k1.y, v1.y, a1);
    a1 = dot2(k1.z, v1.z, a1); a1 = dot2(k1.w, v1.w, a1);
    a2 = dot2(k2.x, v2.x, a2); a2 = dot2(k2.y, v2.y, a2);
    a2 = dot2(k2.z, v2.z, a2); a2 = dot2(k2.w, v2.w, a2);
    a3 = dot2(k3.x, v3.x, a3); a3 = dot2(k3.y, v3.y, a3);
    a3 = dot2(k3.z, v3.z, a3); a3 = dot2(k3.w, v3.w, a3);
    float acc = (a0 + a1) + (a2 + a3);

#pragma unroll
    for (int off = 32; off > 0; off >>= 1) acc += __shfl_down(acc, off, 64);
    if (lane == 0) part[w] = acc;
    __syncthreads();

    if (tid < 8) {
        const int row = blockIdx.x * 8 + tid;
        float r = A_MARG / (part[2 * tid] + part[2 * tid + 1]);
        w32_out[row] = r;
        w16_out[row] = __float2half(r);
    }
}

__global__ void __launch_bounds__(1024, 8)
rowpass_v(const __half* __restrict__ Mat, const __half* __restrict__ w16_in,
          float* __restrict__ w32_out, __half* __restrict__ w16_out,
          unsigned short* __restrict__ hist,
          unsigned* __restrict__ conv, unsigned* __restrict__ slot, int t) {
    if (ld_dev_u32(conv)) return;

    __shared__ __align__(16) __half vlds[MM];
    __shared__ float part[16];
    const int tid  = threadIdx.x;
    const int lane = tid & 63;
    const int w    = tid >> 6;
    const int rib  = w >> 1;
    const int hlf  = w & 1;
    const int i    = blockIdx.x * 8 + rib;
    const uint4* __restrict__ Mrow = (const uint4*)(Mat + (size_t)i * MM);
    const int g0 = hlf * 256 + lane;

    uint4 stg;
    if (tid < 512) stg = ((const uint4*)w16_in)[tid];
    const uint4 k0 = Mrow[g0];
    const uint4 k1 = Mrow[g0 + 64];
    const uint4 k2 = Mrow[g0 + 128];
    const uint4 k3 = Mrow[g0 + 192];
    if (tid < 512) ((uint4*)vlds)[tid] = stg;
    __syncthreads();

    const uint4* V = (const uint4*)vlds;
    const uint4 v0 = V[g0];
    const uint4 v1 = V[g0 + 64];
    const uint4 v2 = V[g0 + 128];
    const uint4 v3 = V[g0 + 192];

    float a0 = 0.f, a1 = 0.f, a2 = 0.f, a3 = 0.f;
    a0 = dot2(k0.x, v0.x, a0); a0 = dot2(k0.y, v0.y, a0);
    a0 = dot2(k0.z, v0.z, a0); a0 = dot2(k0.w, v0.w, a0);
    a1 = dot2(k1.x, v1.x, a1); a1 = dot2(k1.y, v1.y, a1);
    a1 = dot2(k1.z, v1.z, a1); a1 = dot2(k1.w, v1.w, a1);
    a2 = dot2(k2.x, v2.x, a2); a2 = dot2(k2.y, v2.y, a2);
    a2 = dot2(k2.z, v2.z, a2); a2 = dot2(k2.w, v2.w, a2);
    a3 = dot2(k3.x, v3.x, a3); a3 = dot2(k3.y, v3.y, a3);
    a3 = dot2(k3.z, v3.z, a3); a3 = dot2(k3.w, v3.w, a3);
    float acc = (a0 + a1) + (a2 + a3);

#pragma unroll
    for (int off = 32; off > 0; off >>= 1) acc += __shfl_down(acc, off, 64);
    if (lane == 0) part[w] = acc;
    __syncthreads();

    if (tid < 8) {
        const int row = blockIdx.x * 8 + tid;
        float r = B_MARG / (part[2 * tid] + part[2 * tid + 1]);
        w32_out[row] = r;
        const __half h = __float2half(r);
        if (t & 1) {
            const unsigned short bits = __half_as_ushort(h);
            const unsigned short old2 = ld_dev_u16(hist + row);
            if (old2 != bits) st_dev_u32(slot, 1u);
            st_dev_u16(hist + row, bits);
        }
        w16_out[row] = h;
    }
}

// ---------------------------------------------------------------------------
// gamma[i][j] = u[i] * exp(-||x_i-y_j||^2/reg) * v[j]   (exact fp32 K)
// grid: (16, 256), block 256
// ---------------------------------------------------------------------------
__global__ void epilogue(const float* __restrict__ x, const float* __restrict__ y,
                         const float* __restrict__ u, const float* __restrict__ v,
                         float* __restrict__ out) {
    const int tid = threadIdx.x;
    const int j   = blockIdx.x * 256 + tid;
    const int r0  = blockIdx.y * 16;

    float yv[DD];
    const float4* y4 = (const float4*)(y + (size_t)j * DD);
#pragma unroll
    for (int k = 0; k < DD / 4; ++k) {
        float4 t = y4[k];
        yv[4 * k + 0] = t.x; yv[4 * k + 1] = t.y;
        yv[4 * k + 2] = t.z; yv[4 * k + 3] = t.w;
    }

    __shared__ float xs[16 * DD];
    __shared__ float u_lds[16];
    xs[tid]       = x[(size_t)r0 * DD + tid];
    xs[tid + 256] = x[(size_t)r0 * DD + tid + 256];
    if (tid < 16) u_lds[tid] = u[r0 + tid];
    __syncthreads();

    const float vj = v[j];
#pragma unroll 4
    for (int ii = 0; ii < 16; ++ii) {
        float acc = 0.0f;
#pragma unroll
        for (int k = 0; k < DD; ++k) {
            float d = xs[ii * DD + k] - yv[k];
            acc = fmaf(d, d, acc);
        }
        out[(size_t)(r0 + ii) * MM + j] = u_lds[ii] * __expf(-acc * INV_REG) * vj;
    }
}

extern "C" void kernel_launch(void* const* d_in, const int* in_sizes, int n_in,
                              void* d_out, int out_size, void* d_ws, size_t ws_size,
                              hipStream_t stream) {
    const float* x = (const float*)d_in[0];
    const float* y = (const float*)d_in[1];
    __half*   Kh   = (__half*)d_ws;                    // 32 MB
    __half*   KTh  = Kh + (size_t)NN * MM;             // 32 MB
    float*    u32  = (float*)(KTh + (size_t)NN * MM);  // 16 KB
    float*    v32  = u32 + NN;                         // 16 KB
    __half*   u16  = (__half*)(v32 + MM);              // 8 KB
    __half*   v16  = u16 + NN;                         // 8 KB
    unsigned short* hist = (unsigned short*)(v16 + MM);// 8 KB (0xAA-poison safe)
    unsigned* slot = (unsigned*)(hist + MM);           // 4 B
    unsigned* conv = slot + 1;                         // 4 B (fallback path)
    unsigned* cnt8 = slot + 32;                        // 1 KB barrier counters
    float*    out  = (float*)d_out;

    compute_K_half<<<dim3(MM / 256, NN / 16), 256, 0, stream>>>(x, y, Kh, v16, conv, slot, cnt8, 1);
    compute_K_half<<<dim3(NN / 256, MM / 16), 256, 0, stream>>>(y, x, KTh, v16, conv, slot, cnt8, 0);

    {
        void* args[] = { &Kh, &KTh, &u32, &u16, &v32, &v16, &hist, &slot, &cnt8 };
        hipError_t e = hipLaunchCooperativeKernel((const void*)sinkhorn_persist,
                                                  dim3(512), dim3(1024), args, 0, stream);
        if (e != hipSuccess) {
            (void)hipGetLastError();   // clear; fall back to per-iteration dispatches
            for (int t = 0; t < N_ITERS; ++t) {
                rowpass_u<<<NN / 8, 1024, 0, stream>>>(Kh,  v16, u32, u16, conv, slot, t);
                rowpass_v<<<MM / 8, 1024, 0, stream>>>(KTh, u16, v32, v16, hist, conv, slot, t);
            }
        }
    }

    epilogue<<<dim3(MM / 256, NN / 16), 256, 0, stream>>>(x, y, u32, v32, out);
}

// Round 6
// 621.396 us; speedup vs baseline: 1.9427x; 1.0260x over previous
//
#include <hip/hip_runtime.h>
#include <hip/hip_fp16.h>

// Sinkhorn OT: n=m=4096, d=32, reg=0.1, 100 iterations, uniform marginals.
// R11 = R10 persistent cooperative kernel with the grid barrier REPLACED by
// direct data-flow MAILBOXES. R10 post-mortem: kernel is sync-latency-bound
// (96% L2 hit on matrix; NT-load cache shift moved runtime only 3%); the
// per-half-pass critical path was store-drain -> barrier counter RT -> poll
// -> uncached stage RT. New scheme:
//   - each block publishes its 8 fp16 outputs as a 16B mailbox entry
//     (2x u64 agent atomics), then vmcnt(0), then a phase TAG (u32). Tag
//     visibility implies data validity: the tag IS the barrier.
//   - readers: 512 threads poll their entry's tag (==want), compiler barrier,
//     then load 16B data straight into LDS. One fewer fabric RT per half-pass.
//   - slot-reuse safety (depth 2): writer(p+2) read all of p+1 => all blocks
//     wrote p+1 => all blocks finished reading p. Tags monotone increasing;
//     0xAA ws-poison never equals a valid tag (bit31 masked).
//   - freeze detection rides IN the tag: v-writer sets bit31 if its 8 rows
//     bitwise-match hist (v(t)==v(t-2)); readers AND all 512 bits via __all
//     + LDS -> uniform exact break. No slot broadcast reads at all.
//   - wave 0 prefetches matrix rows AFTER its tag publish (so the vmcnt(0)
//     drain doesn't wait on matrix loads); waves 1-15 prefetch before sync.
// Numerics bit-identical to R6..R10 (same dot order, same IEEE divides).
// Fallback: R6 per-iteration dispatch loop if cooperative launch fails.

#define NN 4096
#define MM 4096
#define DD 32
#define N_ITERS 100

static constexpr float INV_REG = 10.0f;
static constexpr float A_MARG  = 1.0f / 4096.0f;
static constexpr float B_MARG  = 1.0f / 4096.0f;

typedef _Float16 h2_t __attribute__((ext_vector_type(2)));
typedef unsigned u32v4 __attribute__((ext_vector_type(4)));

static __device__ __forceinline__ float dot2(unsigned a, unsigned b, float acc) {
#if __has_builtin(__builtin_amdgcn_fdot2)
    return __builtin_amdgcn_fdot2(__builtin_bit_cast(h2_t, a),
                                  __builtin_bit_cast(h2_t, b), acc, false);
#else
    float2 fa = __half22float2(*(const __half2*)&a);
    float2 fb = __half22float2(*(const __half2*)&b);
    acc = fmaf(fa.x, fb.x, acc);
    return fmaf(fa.y, fb.y, acc);
#endif
}

// Non-temporal 16B load (K^T streaming: no L2 allocation).
static __device__ __forceinline__ uint4 ld_nt_u4(const uint4* p) {
#if __has_builtin(__builtin_nontemporal_load)
    u32v4 r = __builtin_nontemporal_load((const u32v4*)p);
    uint4 o; o.x = r[0]; o.y = r[1]; o.z = r[2]; o.w = r[3];
    return o;
#else
    return *p;
#endif
}

static __device__ __forceinline__ unsigned ld_dev_u32(const unsigned* p) {
    return __hip_atomic_load(p, __ATOMIC_RELAXED, __HIP_MEMORY_SCOPE_AGENT);
}
static __device__ __forceinline__ void st_dev_u32(unsigned* p, unsigned v) {
    __hip_atomic_store(p, v, __ATOMIC_RELAXED, __HIP_MEMORY_SCOPE_AGENT);
}
static __device__ __forceinline__ unsigned short ld_dev_u16(const unsigned short* p) {
    return __hip_atomic_load(p, __ATOMIC_RELAXED, __HIP_MEMORY_SCOPE_AGENT);
}
static __device__ __forceinline__ void st_dev_u16(unsigned short* p, unsigned short v) {
    __hip_atomic_store(p, v, __ATOMIC_RELAXED, __HIP_MEMORY_SCOPE_AGENT);
}
static __device__ __forceinline__ unsigned long long ld_dev_u64(const unsigned long long* p) {
    return __hip_atomic_load(p, __ATOMIC_RELAXED, __HIP_MEMORY_SCOPE_AGENT);
}
static __device__ __forceinline__ void st_dev_u64(unsigned long long* p, unsigned long long v) {
    __hip_atomic_store(p, v, __ATOMIC_RELAXED, __HIP_MEMORY_SCOPE_AGENT);
}

// ---------------------------------------------------------------------------
// Kh[i][j] = (half)exp(-||p_i - q_j||^2 / reg). prime!=0: v16=1/4096,
// conv=0, slot=1 (fallback path), mailbox tags zeroed.
// grid: (4096/256, 4096/16), block 256
// ---------------------------------------------------------------------------
__global__ void compute_K_half(const float* __restrict__ p, const float* __restrict__ q,
                               __half* __restrict__ Kh, __half* __restrict__ v16,
                               unsigned* __restrict__ conv, unsigned* __restrict__ slot,
                               unsigned* __restrict__ mtu, unsigned* __restrict__ mtv,
                               int prime) {
    const int tid = threadIdx.x;
    const int j   = blockIdx.x * 256 + tid;
    const int r0  = blockIdx.y * 16;

    if (prime && blockIdx.y == 0) {
        v16[j] = __float2half(B_MARG);
        if (blockIdx.x == 0) {
            if (tid == 0) { *conv = 0u; *slot = 1u; }
            mtu[tid] = 0u; mtu[tid + 256] = 0u;
            mtv[tid] = 0u; mtv[tid + 256] = 0u;
        }
    }

    float qv[DD];
    const float4* q4 = (const float4*)(q + (size_t)j * DD);
#pragma unroll
    for (int k = 0; k < DD / 4; ++k) {
        float4 t = q4[k];
        qv[4 * k + 0] = t.x; qv[4 * k + 1] = t.y;
        qv[4 * k + 2] = t.z; qv[4 * k + 3] = t.w;
    }

    __shared__ float ps[16 * DD];
    ps[tid]       = p[(size_t)r0 * DD + tid];
    ps[tid + 256] = p[(size_t)r0 * DD + tid + 256];
    __syncthreads();

#pragma unroll 4
    for (int ii = 0; ii < 16; ++ii) {
        float acc = 0.0f;
#pragma unroll
        for (int k = 0; k < DD; ++k) {
            float d = ps[ii * DD + k] - qv[k];
            acc = fmaf(d, d, acc);
        }
        Kh[(size_t)(r0 + ii) * MM + j] = __float2half(__expf(-acc * INV_REG));
    }
}

// ---------------------------------------------------------------------------
// Persistent kernel: all 100 iterations, mailbox-synced (no grid barrier).
// 512 blocks x 1024 thr (16 waves), 2 waves per row, 4 fdot2 chains,
// bit-identical accumulation order to R6..R10.
// ---------------------------------------------------------------------------
__global__ void __launch_bounds__(1024, 8)
sinkhorn_persist(const __half* __restrict__ Kh, const __half* __restrict__ KTh,
                 float* __restrict__ u32g, float* __restrict__ v32g,
                 unsigned short* __restrict__ hist,
                 unsigned* __restrict__ mtu, unsigned* __restrict__ mtv,
                 unsigned long long* __restrict__ mdu,
                 unsigned long long* __restrict__ mdv) {
    __shared__ __align__(16) __half vlds[MM];
    __shared__ float part[16];
    __shared__ unsigned fb_lds[8];
    const int tid  = threadIdx.x;
    const int lane = tid & 63;
    const int w    = tid >> 6;          // wave 0..15
    const int rib  = w >> 1;            // row-in-block 0..7
    const int hlf  = w & 1;             // half-row
    const int bid  = blockIdx.x;
    const int i    = bid * 8 + rib;
    const int g0   = hlf * 256 + lane;  // uint4 index into 512-uint4 row
    const uint4* __restrict__ MU = (const uint4*)(Kh  + (size_t)i * MM);
    const uint4* __restrict__ MV = (const uint4*)(KTh + (size_t)i * MM);

    // prefetch u-half matrix rows for t=0
    uint4 k0 = MU[g0], k1 = MU[g0 + 64], k2 = MU[g0 + 128], k3 = MU[g0 + 192];

    for (int t = 0; t < N_ITERS; ++t) {
        // ================= u-half stage: v(t-1) =================
        if (t == 0) {
            if (tid < 512) {
                const unsigned long long dv =
                    (unsigned long long)__half_as_ushort(__float2half(B_MARG)) *
                    0x0001000100010001ULL;
                ((unsigned long long*)vlds)[2 * tid]     = dv;
                ((unsigned long long*)vlds)[2 * tid + 1] = dv;
            }
            __syncthreads();
        } else {
            if (tid < 512) {
                const unsigned want = 2u * (unsigned)t;   // v(t-1) tag
                unsigned tg;
                for (;;) {
                    tg = ld_dev_u32(mtv + tid);
                    if ((tg & 0x7fffffffu) == want) break;
                    __builtin_amdgcn_s_sleep(1);
                }
                asm volatile("" ::: "memory");   // no hoist of data loads above poll
                unsigned long long d0 = ld_dev_u64(mdv + 2 * tid);
                unsigned long long d1 = ld_dev_u64(mdv + 2 * tid + 1);
                ((unsigned long long*)vlds)[2 * tid]     = d0;
                ((unsigned long long*)vlds)[2 * tid + 1] = d1;
                const bool allf = __all((tg >> 31) != 0u);
                if ((tid & 63) == 0) fb_lds[tid >> 6] = allf ? 1u : 0u;
            }
            __syncthreads();
            if ((t & 1) == 0) {
                // v(t-1) == v(t-3) bitwise everywhere -> all remaining
                // iterations bit-identical; skipping them is exact.
                if ((fb_lds[0] & fb_lds[1] & fb_lds[2] & fb_lds[3] &
                     fb_lds[4] & fb_lds[5] & fb_lds[6] & fb_lds[7]) != 0u)
                    break;
            }
        }

        // ================= u-half compute: u = a / (Kh . v) =================
        {
            const uint4* V = (const uint4*)vlds;
            const uint4 a = V[g0], b = V[g0 + 64], c = V[g0 + 128], d = V[g0 + 192];
            float x0 = 0.f, x1 = 0.f, x2 = 0.f, x3 = 0.f;
            x0 = dot2(k0.x, a.x, x0); x0 = dot2(k0.y, a.y, x0);
            x0 = dot2(k0.z, a.z, x0); x0 = dot2(k0.w, a.w, x0);
            x1 = dot2(k1.x, b.x, x1); x1 = dot2(k1.y, b.y, x1);
            x1 = dot2(k1.z, b.z, x1); x1 = dot2(k1.w, b.w, x1);
            x2 = dot2(k2.x, c.x, x2); x2 = dot2(k2.y, c.y, x2);
            x2 = dot2(k2.z, c.z, x2); x2 = dot2(k2.w, c.w, x2);
            x3 = dot2(k3.x, d.x, x3); x3 = dot2(k3.y, d.y, x3);
            x3 = dot2(k3.z, d.z, x3); x3 = dot2(k3.w, d.w, x3);
            float acc = (x0 + x1) + (x2 + x3);
#pragma unroll
            for (int off = 32; off > 0; off >>= 1) acc += __shfl_down(acc, off, 64);
            if (lane == 0) part[w] = acc;
        }
        // waves 1..15: prefetch v-half rows now (overlaps finalize+poll)
        if (w != 0) {
            k0 = ld_nt_u4(MV + g0);       k1 = ld_nt_u4(MV + g0 + 64);
            k2 = ld_nt_u4(MV + g0 + 128); k3 = ld_nt_u4(MV + g0 + 192);
        }
        __syncthreads();
        if (tid == 0) {   // finalize: publish u(t) mailbox entry
            unsigned long long d0 = 0, d1 = 0;
#pragma unroll
            for (int q = 0; q < 8; ++q) {
                float r = A_MARG / (part[2 * q] + part[2 * q + 1]);
                u32g[bid * 8 + q] = r;
                const unsigned long long h =
                    (unsigned long long)__half_as_ushort(__float2half(r));
                if (q < 4) d0 |= h << (16 * q); else d1 |= h << (16 * (q - 4));
            }
            st_dev_u64(mdu + 2 * bid,     d0);
            st_dev_u64(mdu + 2 * bid + 1, d1);
            asm volatile("s_waitcnt vmcnt(0)" ::: "memory");   // data at coherence pt
            st_dev_u32(mtu + bid, 2u * (unsigned)t + 1u);      // then tag
        }
        // wave 0: prefetch AFTER tag publish (keeps vmcnt(0) drain cheap)
        if (w == 0) {
            k0 = ld_nt_u4(MV + g0);       k1 = ld_nt_u4(MV + g0 + 64);
            k2 = ld_nt_u4(MV + g0 + 128); k3 = ld_nt_u4(MV + g0 + 192);
        }

        // ================= v-half stage: u(t) =================
        if (tid < 512) {
            const unsigned want = 2u * (unsigned)t + 1u;   // u(t) tag
            unsigned tg;
            for (;;) {
                tg = ld_dev_u32(mtu + tid);
                if ((tg & 0x7fffffffu) == want) break;
                __builtin_amdgcn_s_sleep(1);
            }
            asm volatile("" ::: "memory");
            unsigned long long d0 = ld_dev_u64(mdu + 2 * tid);
            unsigned long long d1 = ld_dev_u64(mdu + 2 * tid + 1);
            ((unsigned long long*)vlds)[2 * tid]     = d0;
            ((unsigned long long*)vlds)[2 * tid + 1] = d1;
        }
        __syncthreads();

        // ================= v-half compute: v = b / (KTh . u) =================
        {
            const uint4* V = (const uint4*)vlds;
            const uint4 a = V[g0], b = V[g0 + 64], c = V[g0 + 128], d = V[g0 + 192];
            float x0 = 0.f, x1 = 0.f, x2 = 0.f, x3 = 0.f;
            x0 = dot2(k0.x, a.x, x0); x0 = dot2(k0.y, a.y, x0);
            x0 = dot2(k0.z, a.z, x0); x0 = dot2(k0.w, a.w, x0);
            x1 = dot2(k1.x, b.x, x1); x1 = dot2(k1.y, b.y, x1);
            x1 = dot2(k1.z, b.z, x1); x1 = dot2(k1.w, b.w, x1);
            x2 = dot2(k2.x, c.x, x2); x2 = dot2(k2.y, c.y, x2);
            x2 = dot2(k2.z, c.z, x2); x2 = dot2(k2.w, c.w, x2);
            x3 = dot2(k3.x, d.x, x3); x3 = dot2(k3.y, d.y, x3);
            x3 = dot2(k3.z, d.z, x3); x3 = dot2(k3.w, d.w, x3);
            float acc = (x0 + x1) + (x2 + x3);
#pragma unroll
            for (int off = 32; off > 0; off >>= 1) acc += __shfl_down(acc, off, 64);
            if (lane == 0) part[w] = acc;
        }
        // waves 1..15: prefetch next u-half rows (plain cached)
        if (w != 0) {
            k0 = MU[g0]; k1 = MU[g0 + 64]; k2 = MU[g0 + 128]; k3 = MU[g0 + 192];
        }
        __syncthreads();
        if (tid == 0) {   // finalize: publish v(t) mailbox entry (+freeze bit)
            unsigned long long d0 = 0, d1 = 0;
#pragma unroll
            for (int q = 0; q < 8; ++q) {
                float r = B_MARG / (part[2 * q] + part[2 * q + 1]);
                v32g[bid * 8 + q] = r;
                const unsigned long long h =
                    (unsigned long long)__half_as_ushort(__float2half(r));
                if (q < 4) d0 |= h << (16 * q); else d1 |= h << (16 * (q - 4));
            }
            unsigned tg = 2u * (unsigned)t + 2u;
            if (t & 1) {   // compare vs v(t-2) (same parity); 0xAA poison safe
                unsigned long long h0 = ld_dev_u64((unsigned long long*)hist + 2 * bid);
                unsigned long long h1 = ld_dev_u64((unsigned long long*)hist + 2 * bid + 1);
                if (h0 == d0 && h1 == d1) tg |= 0x80000000u;
                st_dev_u64((unsigned long long*)hist + 2 * bid,     d0);
                st_dev_u64((unsigned long long*)hist + 2 * bid + 1, d1);
            }
            st_dev_u64(mdv + 2 * bid,     d0);
            st_dev_u64(mdv + 2 * bid + 1, d1);
            asm volatile("s_waitcnt vmcnt(0)" ::: "memory");
            st_dev_u32(mtv + bid, tg);
        }
        if (w == 0) {
            k0 = MU[g0]; k1 = MU[g0 + 64]; k2 = MU[g0 + 128]; k3 = MU[g0 + 192];
        }
    }
}

// ---------------------------------------------------------------------------
// Fallback per-iteration rowpasses (identical to R6; used only if the
// cooperative launch is rejected under graph capture).
// ---------------------------------------------------------------------------
__global__ void __launch_bounds__(1024, 8)
rowpass_u(const __half* __restrict__ Mat, const __half* __restrict__ w16_in,
          float* __restrict__ w32_out, __half* __restrict__ w16_out,
          unsigned* __restrict__ conv, unsigned* __restrict__ slot, int t) {
    if (ld_dev_u32(conv)) return;
    if ((t & 1) == 0) {
        if (ld_dev_u32(slot) == 0u) {
            if (threadIdx.x == 0) st_dev_u32(conv, 1u);
            return;
        }
    } else {
        if (blockIdx.x == 0 && threadIdx.x == 0) st_dev_u32(slot, 0u);
    }

    __shared__ __align__(16) __half vlds[MM];
    __shared__ float part[16];
    const int tid  = threadIdx.x;
    const int lane = tid & 63;
    const int w    = tid >> 6;
    const int rib  = w >> 1;
    const int hlf  = w & 1;
    const int i    = blockIdx.x * 8 + rib;
    const uint4* __restrict__ Mrow = (const uint4*)(Mat + (size_t)i * MM);
    const int g0 = hlf * 256 + lane;

    uint4 stg;
    if (tid < 512) stg = ((const uint4*)w16_in)[tid];
    const uint4 k0 = Mrow[g0];
    const uint4 k1 = Mrow[g0 + 64];
    const uint4 k2 = Mrow[g0 + 128];
    const uint4 k3 = Mrow[g0 + 192];
    if (tid < 512) ((uint4*)vlds)[tid] = stg;
    __syncthreads();

    const uint4* V = (const uint4*)vlds;
    const uint4 v0 = V[g0];
    const uint4 v1 = V[g0 + 64];
    const uint4 v2 = V[g0 + 128];
    const uint4 v3 = V[g0 + 192];

    float a0 = 0.f, a1 = 0.f, a2 = 0.f, a3 = 0.f;
    a0 = dot2(k0.x, v0.x, a0); a0 = dot2(k0.y, v0.y, a0);
    a0 = dot2(k0.z, v0.z, a0); a0 = dot2(k0.w, v0.w, a0);
    a1 = dot2(k1.x, v1.x, a1); a1 = dot2(k1.y, v1.y, a1);
    a1 = dot2(k1.z, v1.z, a1); a1 = dot2(k1.w, v1.w, a1);
    a2 = dot2(k2.x, v2.x, a2); a2 = dot2(k2.y, v2.y, a2);
    a2 = dot2(k2.z, v2.z, a2); a2 = dot2(k2.w, v2.w, a2);
    a3 = dot2(k3.x, v3.x, a3); a3 = dot2(k3.y, v3.y, a3);
    a3 = dot2(k3.z, v3.z, a3); a3 = dot2(k3.w, v3.w, a3);
    float acc = (a0 + a1) + (a2 + a3);

#pragma unroll
    for (int off = 32; off > 0; off >>= 1) acc += __shfl_down(acc, off, 64);
    if (lane == 0) part[w] = acc;
    __syncthreads();

    if (tid < 8) {
        const int row = blockIdx.x * 8 + tid;
        float r = A_MARG / (part[2 * tid] + part[2 * tid + 1]);
        w32_out[row] = r;
        w16_out[row] = __float2half(r);
    }
}

__global__ void __launch_bounds__(1024, 8)
rowpass_v(const __half* __restrict__ Mat, const __half* __restrict__ w16_in,
          float* __restrict__ w32_out, __half* __restrict__ w16_out,
          unsigned short* __restrict__ hist,
          unsigned* __restrict__ conv, unsigned* __restrict__ slot, int t) {
    if (ld_dev_u32(conv)) return;

    __shared__ __align__(16) __half vlds[MM];
    __shared__ float part[16];
    const int tid  = threadIdx.x;
    const int lane = tid & 63;
    const int w    = tid >> 6;
    const int rib  = w >> 1;
    const int hlf  = w & 1;
    const int i    = blockIdx.x * 8 + rib;
    const uint4* __restrict__ Mrow = (const uint4*)(Mat + (size_t)i * MM);
    const int g0 = hlf * 256 + lane;

    uint4 stg;
    if (tid < 512) stg = ((const uint4*)w16_in)[tid];
    const uint4 k0 = Mrow[g0];
    const uint4 k1 = Mrow[g0 + 64];
    const uint4 k2 = Mrow[g0 + 128];
    const uint4 k3 = Mrow[g0 + 192];
    if (tid < 512) ((uint4*)vlds)[tid] = stg;
    __syncthreads();

    const uint4* V = (const uint4*)vlds;
    const uint4 v0 = V[g0];
    const uint4 v1 = V[g0 + 64];
    const uint4 v2 = V[g0 + 128];
    const uint4 v3 = V[g0 + 192];

    float a0 = 0.f, a1 = 0.f, a2 = 0.f, a3 = 0.f;
    a0 = dot2(k0.x, v0.x, a0); a0 = dot2(k0.y, v0.y, a0);
    a0 = dot2(k0.z, v0.z, a0); a0 = dot2(k0.w, v0.w, a0);
    a1 = dot2(k1.x, v1.x, a1); a1 = dot2(k1.y, v1.y, a1);
    a1 = dot2(k1.z, v1.z, a1); a1 = dot2(k1.w, v1.w, a1);
    a2 = dot2(k2.x, v2.x, a2); a2 = dot2(k2.y, v2.y, a2);
    a2 = dot2(k2.z, v2.z, a2); a2 = dot2(k2.w, v2.w, a2);
    a3 = dot2(k3.x, v3.x, a3); a3 = dot2(k3.y, v3.y, a3);
    a3 = dot2(k3.z, v3.z, a3); a3 = dot2(k3.w, v3.w, a3);
    float acc = (a0 + a1) + (a2 + a3);

#pragma unroll
    for (int off = 32; off > 0; off >>= 1) acc += __shfl_down(acc, off, 64);
    if (lane == 0) part[w] = acc;
    __syncthreads();

    if (tid < 8) {
        const int row = blockIdx.x * 8 + tid;
        float r = B_MARG / (part[2 * tid] + part[2 * tid + 1]);
        w32_out[row] = r;
        const __half h = __float2half(r);
        if (t & 1) {
            const unsigned short bits = __half_as_ushort(h);
            const unsigned short old2 = ld_dev_u16(hist + row);
            if (old2 != bits) st_dev_u32(slot, 1u);
            st_dev_u16(hist + row, bits);
        }
        w16_out[row] = h;
    }
}

// ---------------------------------------------------------------------------
// gamma[i][j] = u[i] * exp(-||x_i-y_j||^2/reg) * v[j]   (exact fp32 K)
// grid: (16, 256), block 256
// ---------------------------------------------------------------------------
__global__ void epilogue(const float* __restrict__ x, const float* __restrict__ y,
                         const float* __restrict__ u, const float* __restrict__ v,
                         float* __restrict__ out) {
    const int tid = threadIdx.x;
    const int j   = blockIdx.x * 256 + tid;
    const int r0  = blockIdx.y * 16;

    float yv[DD];
    const float4* y4 = (const float4*)(y + (size_t)j * DD);
#pragma unroll
    for (int k = 0; k < DD / 4; ++k) {
        float4 t = y4[k];
        yv[4 * k + 0] = t.x; yv[4 * k + 1] = t.y;
        yv[4 * k + 2] = t.z; yv[4 * k + 3] = t.w;
    }

    __shared__ float xs[16 * DD];
    __shared__ float u_lds[16];
    xs[tid]       = x[(size_t)r0 * DD + tid];
    xs[tid + 256] = x[(size_t)r0 * DD + tid + 256];
    if (tid < 16) u_lds[tid] = u[r0 + tid];
    __syncthreads();

    const float vj = v[j];
#pragma unroll 4
    for (int ii = 0; ii < 16; ++ii) {
        float acc = 0.0f;
#pragma unroll
        for (int k = 0; k < DD; ++k) {
            float d = xs[ii * DD + k] - yv[k];
            acc = fmaf(d, d, acc);
        }
        out[(size_t)(r0 + ii) * MM + j] = u_lds[ii] * __expf(-acc * INV_REG) * vj;
    }
}

extern "C" void kernel_launch(void* const* d_in, const int* in_sizes, int n_in,
                              void* d_out, int out_size, void* d_ws, size_t ws_size,
                              hipStream_t stream) {
    const float* x = (const float*)d_in[0];
    const float* y = (const float*)d_in[1];
    __half*   Kh   = (__half*)d_ws;                    // 32 MB
    __half*   KTh  = Kh + (size_t)NN * MM;             // 32 MB
    float*    u32  = (float*)(KTh + (size_t)NN * MM);  // 16 KB
    float*    v32  = u32 + NN;                         // 16 KB
    __half*   u16  = (__half*)(v32 + MM);              // 8 KB (fallback)
    __half*   v16  = u16 + NN;                         // 8 KB (fallback)
    unsigned short* hist = (unsigned short*)(v16 + MM);// 8 KB (0xAA-poison safe)
    unsigned* slot = (unsigned*)(hist + MM);           // 4 B (fallback)
    unsigned* conv = slot + 1;                         // 4 B (fallback)
    unsigned* mtu  = slot + 512;                       // 2 KB u-tags
    unsigned* mtv  = mtu + 512;                        // 2 KB v-tags
    unsigned long long* mdu = (unsigned long long*)(mtv + 512);  // 8 KB u-data
    unsigned long long* mdv = mdu + 1024;                        // 8 KB v-data
    float*    out  = (float*)d_out;

    compute_K_half<<<dim3(MM / 256, NN / 16), 256, 0, stream>>>(x, y, Kh, v16, conv, slot, mtu, mtv, 1);
    compute_K_half<<<dim3(NN / 256, MM / 16), 256, 0, stream>>>(y, x, KTh, v16, conv, slot, mtu, mtv, 0);

    {
        void* args[] = { &Kh, &KTh, &u32, &v32, &hist, &mtu, &mtv, &mdu, &mdv };
        hipError_t e = hipLaunchCooperativeKernel((const void*)sinkhorn_persist,
                                                  dim3(512), dim3(1024), args, 0, stream);
        if (e != hipSuccess) {
            (void)hipGetLastError();   // clear; fall back to per-iteration dispatches
            for (int t = 0; t < N_ITERS; ++t) {
                rowpass_u<<<NN / 8, 1024, 0, stream>>>(Kh,  v16, u32, u16, conv, slot, t);
                rowpass_v<<<MM / 8, 1024, 0, stream>>>(KTh, u16, v32, v16, hist, conv, slot, t);
            }
        }
    }

    epilogue<<<dim3(MM / 256, NN / 16), 256, 0, stream>>>(x, y, u32, v32, out);
}